// Round 10
// baseline (512.493 us; speedup 1.0000x reference)
//
#include <hip/hip_runtime.h>

constexpr int N_NODES = 50000;
constexpr int N_EDGES = 800000;
constexpr int D = 64;

constexpr int NREG = 512;    // destination regions (one gin block each)
constexpr int RSZ = 98;      // nodes per region (512*98 = 50176 >= 50000)
constexpr int EPB = 4096;    // edges per prep block
constexpr int NBINB = 196;   // ceil(800000/4096)
constexpr int CELLCAP = 32;  // per-(region,block) cell cap; mean 8, P(>32) ~ 1e-10
constexpr int ASTR = 68;     // acc row stride (floats): pad 64+4, float4-aligned,
                             // breaks stride-64 bank aliasing

// Workspace layout (ints):
//   cnt2 [NREG*NBINB]          at int 0        (400 KB)
//   rbuf [NREG*NBINB*CELLCAP]  at int 100352   (12.8 MB, 128B cells)
constexpr int WS_CNT2 = 0;
constexpr int WS_RBUF = NREG * NBINB;  // 100352

using vfloat4 = __attribute__((ext_vector_type(4))) float;  // native vec for NT ops

// Edge binning only: packed word = (dst_local << 16) | src, appended to the
// (region, block) cell via LDS cursors. No global atomics.
__global__ __launch_bounds__(1024) void prep_kernel(
    const int* __restrict__ src, const int* __restrict__ dst,
    int* __restrict__ cnt2, unsigned* __restrict__ rbuf) {
  __shared__ int cur[NREG];
  int tid = threadIdx.x, blk = blockIdx.x;
  if (tid < NREG) cur[tid] = 0;

  int e0 = blk * EPB + tid * 4;
  bool valid = (e0 + 4 <= N_EDGES);  // N_EDGES % 4 == 0
  int4 d4 = {0, 0, 0, 0}, s4 = {0, 0, 0, 0};
  if (valid) {
    d4 = *reinterpret_cast<const int4*>(dst + e0);
    s4 = *reinterpret_cast<const int4*>(src + e0);
  }
  __syncthreads();

  if (valid) {
    const int dd[4] = {d4.x, d4.y, d4.z, d4.w};
    const int ss[4] = {s4.x, s4.y, s4.z, s4.w};
#pragma unroll
    for (int k = 0; k < 4; ++k) {
      int r = dd[k] / RSZ;  // magic-mul
      unsigned pk = ((unsigned)(dd[k] - r * RSZ) << 16) | (unsigned)ss[k];
      int p = atomicAdd(&cur[r], 1);
      if (p < CELLCAP)
        rbuf[(size_t)(r * NBINB + blk) * CELLCAP + p] = pk;
    }
  }
  __syncthreads();
  if (tid < NREG) {
    int c = cur[tid];
    cnt2[tid * NBINB + blk] = (c > CELLCAP) ? CELLCAP : c;
  }
}

// One block per region (512 x 512 = 2 blocks/CU). No sort: edges are applied
// in arrival order into fp32 LDS accumulators (ds_add_f32), which are
// initialized with (1+eps)*feat. Then a register-blocked matvec with Wt.
__global__ __launch_bounds__(512) void gin_kernel(
    const float* __restrict__ feat, const float* __restrict__ W,
    const float* __restrict__ b, const float* __restrict__ eps,
    const int* __restrict__ cnt2, const unsigned* __restrict__ rbuf,
    float* __restrict__ out) {
  __shared__ float Wt[D * D];             // 16 KB: Wt[i*64+o] = W[o*64+i]
  __shared__ float acc[RSZ * ASTR];       // 26 KB: neigh + (1+eps)*feat
  __shared__ unsigned ebuf[NBINB * CELLCAP];  // 24.5 KB: region edges (fixed slots)
  __shared__ int ccnt[NBINB];

  int tid = threadIdx.x, r = blockIdx.x;
  for (int q = tid; q < D * D; q += 512) Wt[q] = W[((q & 63) << 6) + (q >> 6)];
  if (tid < NBINB) ccnt[tid] = cnt2[r * NBINB + tid];

  // Copy full cells (128 B each) into fixed ebuf slots; garbage beyond the
  // count is never read. 4 threads per cell, uint4 moves, no branches.
  for (int cell = tid >> 2; cell < NBINB; cell += 128) {
    int sub = tid & 3;
    const uint4* cp = reinterpret_cast<const uint4*>(
        rbuf + (size_t)(r * NBINB + cell) * CELLCAP);
    uint4 v0 = cp[sub], v1 = cp[sub + 4];
    uint4* ep = reinterpret_cast<uint4*>(ebuf + (cell << 5));
    ep[sub] = v0;
    ep[sub + 4] = v1;
  }

  // Init acc with the eps-scaled self term. Group g owns nodes g, g+32, ...
  int g = tid >> 4, j4 = (tid & 15) << 2;
  float s = 1.0f + eps[0];
  for (int n = g; n < RSZ; n += 32) {
    int node = r * RSZ + n;
    float4 f = {0.f, 0.f, 0.f, 0.f};
    if (node < N_NODES)
      f = *reinterpret_cast<const float4*>(feat + (node << 6) + j4);
    f.x *= s; f.y *= s; f.z *= s; f.w *= s;
    *reinterpret_cast<float4*>(acc + n * ASTR + j4) = f;
  }
  __syncthreads();

  // Edge phase: groups walk cells round-robin; 4 gathers in flight.
  for (int cell = g; cell < NBINB; cell += 32) {
    int cc = ccnt[cell];
    const unsigned* ep = ebuf + (cell << 5);
    int e = 0;
    for (; e + 4 <= cc; e += 4) {
      unsigned p0 = ep[e], p1 = ep[e + 1], p2 = ep[e + 2], p3 = ep[e + 3];
      const float4 f0 = *reinterpret_cast<const float4*>(feat + ((p0 & 0xFFFFu) << 6) + j4);
      const float4 f1 = *reinterpret_cast<const float4*>(feat + ((p1 & 0xFFFFu) << 6) + j4);
      const float4 f2 = *reinterpret_cast<const float4*>(feat + ((p2 & 0xFFFFu) << 6) + j4);
      const float4 f3 = *reinterpret_cast<const float4*>(feat + ((p3 & 0xFFFFu) << 6) + j4);
      float* a0 = acc + (p0 >> 16) * ASTR + j4;
      float* a1 = acc + (p1 >> 16) * ASTR + j4;
      float* a2 = acc + (p2 >> 16) * ASTR + j4;
      float* a3 = acc + (p3 >> 16) * ASTR + j4;
      atomicAdd(a0 + 0, f0.x); atomicAdd(a0 + 1, f0.y);
      atomicAdd(a0 + 2, f0.z); atomicAdd(a0 + 3, f0.w);
      atomicAdd(a1 + 0, f1.x); atomicAdd(a1 + 1, f1.y);
      atomicAdd(a1 + 2, f1.z); atomicAdd(a1 + 3, f1.w);
      atomicAdd(a2 + 0, f2.x); atomicAdd(a2 + 1, f2.y);
      atomicAdd(a2 + 2, f2.z); atomicAdd(a2 + 3, f2.w);
      atomicAdd(a3 + 0, f3.x); atomicAdd(a3 + 1, f3.y);
      atomicAdd(a3 + 2, f3.z); atomicAdd(a3 + 3, f3.w);
    }
    for (; e < cc; ++e) {
      unsigned pk = ep[e];
      const float4 f = *reinterpret_cast<const float4*>(feat + ((pk & 0xFFFFu) << 6) + j4);
      float* a = acc + (pk >> 16) * ASTR + j4;
      atomicAdd(a + 0, f.x); atomicAdd(a + 1, f.y);
      atomicAdd(a + 2, f.z); atomicAdd(a + 3, f.w);
    }
  }
  __syncthreads();

  // Matvec, register-blocked 4 nodes per group: Wt reads amortized 4x.
  {
    int n0 = g, n1 = g + 32, n2 = g + 64, n3 = g + 96;
    int n3c = (n3 < RSZ) ? n3 : 0;  // clamp; store guarded below
    float4 bb = *reinterpret_cast<const float4*>(b + j4);
    float4 r0 = bb, r1 = bb, r2 = bb, r3 = bb;
#pragma unroll
    for (int i4 = 0; i4 < 16; ++i4) {
      const float4 w0 = *reinterpret_cast<const float4*>(Wt + ((i4 << 2) + 0) * D + j4);
      const float4 w1 = *reinterpret_cast<const float4*>(Wt + ((i4 << 2) + 1) * D + j4);
      const float4 w2 = *reinterpret_cast<const float4*>(Wt + ((i4 << 2) + 2) * D + j4);
      const float4 w3 = *reinterpret_cast<const float4*>(Wt + ((i4 << 2) + 3) * D + j4);
      const float4 a0 = *reinterpret_cast<const float4*>(acc + n0 * ASTR + (i4 << 2));
      const float4 a1 = *reinterpret_cast<const float4*>(acc + n1 * ASTR + (i4 << 2));
      const float4 a2 = *reinterpret_cast<const float4*>(acc + n2 * ASTR + (i4 << 2));
      const float4 a3 = *reinterpret_cast<const float4*>(acc + n3c * ASTR + (i4 << 2));
      r0.x += a0.x * w0.x + a0.y * w1.x + a0.z * w2.x + a0.w * w3.x;
      r0.y += a0.x * w0.y + a0.y * w1.y + a0.z * w2.y + a0.w * w3.y;
      r0.z += a0.x * w0.z + a0.y * w1.z + a0.z * w2.z + a0.w * w3.z;
      r0.w += a0.x * w0.w + a0.y * w1.w + a0.z * w2.w + a0.w * w3.w;
      r1.x += a1.x * w0.x + a1.y * w1.x + a1.z * w2.x + a1.w * w3.x;
      r1.y += a1.x * w0.y + a1.y * w1.y + a1.z * w2.y + a1.w * w3.y;
      r1.z += a1.x * w0.z + a1.y * w1.z + a1.z * w2.z + a1.w * w3.z;
      r1.w += a1.x * w0.w + a1.y * w1.w + a1.z * w2.w + a1.w * w3.w;
      r2.x += a2.x * w0.x + a2.y * w1.x + a2.z * w2.x + a2.w * w3.x;
      r2.y += a2.x * w0.y + a2.y * w1.y + a2.z * w2.y + a2.w * w3.y;
      r2.z += a2.x * w0.z + a2.y * w1.z + a2.z * w2.z + a2.w * w3.z;
      r2.w += a2.x * w0.w + a2.y * w1.w + a2.z * w2.w + a2.w * w3.w;
      r3.x += a3.x * w0.x + a3.y * w1.x + a3.z * w2.x + a3.w * w3.x;
      r3.y += a3.x * w0.y + a3.y * w1.y + a3.z * w2.y + a3.w * w3.y;
      r3.z += a3.x * w0.z + a3.y * w1.z + a3.z * w2.z + a3.w * w3.z;
      r3.w += a3.x * w0.w + a3.y * w1.w + a3.z * w2.w + a3.w * w3.w;
    }
    int base = r * RSZ;
    const float4 rr[4] = {r0, r1, r2, r3};
    const int nn[4] = {n0, n1, n2, n3};
#pragma unroll
    for (int k = 0; k < 4; ++k) {
      int node = base + nn[k];
      if (nn[k] < RSZ && node < N_NODES) {
        vfloat4 v;
        v.x = rr[k].x; v.y = rr[k].y; v.z = rr[k].z; v.w = rr[k].w;
        __builtin_nontemporal_store(
            v, reinterpret_cast<vfloat4*>(out + (node << 6) + j4));
      }
    }
  }
}

extern "C" void kernel_launch(void* const* d_in, const int* in_sizes, int n_in,
                              void* d_out, int out_size, void* d_ws, size_t ws_size,
                              hipStream_t stream) {
  const float* feat = (const float*)d_in[0];
  const float* W    = (const float*)d_in[1];
  const float* b    = (const float*)d_in[2];
  const float* eps  = (const float*)d_in[3];
  const int*   src  = (const int*)d_in[4];
  const int*   dst  = (const int*)d_in[5];
  float* out = (float*)d_out;

  int* ws = (int*)d_ws;
  int* cnt2      = ws + WS_CNT2;
  unsigned* rbuf = (unsigned*)(ws + WS_RBUF);

  hipLaunchKernelGGL(prep_kernel, dim3(NBINB), dim3(1024), 0, stream,
                     src, dst, cnt2, rbuf);
  hipLaunchKernelGGL(gin_kernel, dim3(NREG), dim3(512), 0, stream,
                     feat, W, b, eps, cnt2, rbuf, out);
}

// Round 11
// 159.044 us; speedup vs baseline: 3.2223x; 3.2223x over previous
//
#include <hip/hip_runtime.h>
#include <hip/hip_cooperative_groups.h>

namespace cg = cooperative_groups;

constexpr int N_NODES = 50000;
constexpr int N_EDGES = 800000;
constexpr int D = 64;

constexpr int NBLK = 256;    // grid size == regions == bin chunks
constexpr int RSZ = 196;     // nodes per region (256*196 = 50176 >= 50000)
constexpr int EPB = 3125;    // edges per block, phase A (256*3125 == 800000)
constexpr int CELLCAP = 48;  // per-(region,block) cell cap; mean 12.2, ~10 sigma
constexpr int RECAP = 4608;  // per-region edge cap; mean 3125, sigma ~56

// Workspace (ints): cnt2[NBLK*NBLK] at 0 (256 KB); rbuf[NBLK*NBLK*CELLCAP]
// at NBLK*NBLK (12.6 MB, 192B cells, 16B-aligned).
constexpr int WS_CNT2 = 0;
constexpr int WS_RBUF = NBLK * NBLK;

// Single cooperative kernel.
// Phase A: each block bins its contiguous 3125-edge chunk by destination
//   region into private (region, block) cells via LDS int cursors (int LDS
//   atomics are proven cheap; float LDS atomics are NOT — R10 regression).
// grid.sync()
// Phase B: block r = region r. Concat cells -> LDS, counting-sort by local
//   node (int LDS atomics), then per-node fp32 gather + eps-residual +
//   Linear via width-16 shuffles.
__global__ __launch_bounds__(1024) void gin_coop_kernel(
    const float* __restrict__ feat, const float* __restrict__ W,
    const float* __restrict__ b, const float* __restrict__ eps,
    const int* __restrict__ src, const int* __restrict__ dst,
    int* __restrict__ cnt2, unsigned* __restrict__ rbuf,
    float* __restrict__ out) {
  __shared__ float Wt[D * D];       // 16 KB: Wt[i*64+o] = W[o*64+i]
  __shared__ unsigned ebuf[RECAP];  // 18 KB: unsorted region edges
  __shared__ ushort sorted[RECAP];  // 9 KB: src indices sorted by node
  __shared__ int cellstart[NBLK + 1];
  __shared__ int hist[RSZ], nstart[RSZ + 1], cursor[RSZ];
  __shared__ int scan_tmp[256];
  __shared__ int cur[NBLK];

  cg::grid_group grid = cg::this_grid();
  int tid = threadIdx.x, blk = blockIdx.x;

  // ---------------- Phase A: bin edges ----------------
  if (tid < NBLK) cur[tid] = 0;
  __syncthreads();
  int e0 = blk * EPB;
  for (int i = tid; i < EPB; i += 1024) {
    int d = dst[e0 + i];
    int s = src[e0 + i];
    int r = d / RSZ;  // magic-mul
    unsigned pk = ((unsigned)(d - r * RSZ) << 16) | (unsigned)s;
    int p = atomicAdd(&cur[r], 1);
    if (p < CELLCAP) rbuf[(r * NBLK + blk) * CELLCAP + p] = pk;
  }
  // Stage Wt while waiting (independent of phase A data).
  for (int q = tid; q < D * D; q += 1024) Wt[q] = W[((q & 63) << 6) + (q >> 6)];
  __syncthreads();
  if (tid < NBLK) {
    int c = cur[tid];
    cnt2[tid * NBLK + blk] = (c > CELLCAP) ? CELLCAP : c;
  }

  grid.sync();

  // ---------------- Phase B: region r = blk ----------------
  int r = blk;
  if (tid < RSZ) hist[tid] = 0;

  // Scan the region's 256 cell counts (contiguous read; cnt2 region-major).
  int c = (tid < NBLK) ? cnt2[r * NBLK + tid] : 0;
  if (tid < 256) scan_tmp[tid] = c;
  __syncthreads();
  for (int ofs = 1; ofs < 256; ofs <<= 1) {
    int v = 0;
    if (tid < 256 && tid >= ofs) v = scan_tmp[tid - ofs];
    __syncthreads();
    if (tid < 256) scan_tmp[tid] += v;
    __syncthreads();
  }
  if (tid < NBLK) cellstart[tid] = scan_tmp[tid] - c;
  if (tid == NBLK - 1) cellstart[NBLK] = scan_tmp[tid];
  __syncthreads();
  int T = cellstart[NBLK];
  if (T > RECAP) T = RECAP;  // statistically impossible

  // Concatenate cells into ebuf: 4 threads per cell, uint4 loads, one pass.
  {
    int cell = tid >> 2, sub = tid & 3;
    int cs = cellstart[cell];
    int cc = cellstart[cell + 1] - cs;
    const unsigned* cp = rbuf + (size_t)(r * NBLK + cell) * CELLCAP;
    for (int i = sub * 4; i < cc; i += 16) {
      uint4 v = *reinterpret_cast<const uint4*>(cp + i);  // 16B-aligned
      if (cs + i + 0 < T && i + 0 < cc) ebuf[cs + i + 0] = v.x;
      if (cs + i + 1 < T && i + 1 < cc) ebuf[cs + i + 1] = v.y;
      if (cs + i + 2 < T && i + 2 < cc) ebuf[cs + i + 2] = v.z;
      if (cs + i + 3 < T && i + 3 < cc) ebuf[cs + i + 3] = v.w;
    }
  }
  __syncthreads();

  // Counting sort by local node (int LDS atomics).
  for (int e = tid; e < T; e += 1024) atomicAdd(&hist[ebuf[e] >> 16], 1);
  __syncthreads();
  if (tid < 256) scan_tmp[tid] = (tid < RSZ) ? hist[tid] : 0;
  __syncthreads();
  for (int ofs = 1; ofs < 256; ofs <<= 1) {
    int v = 0;
    if (tid < 256 && tid >= ofs) v = scan_tmp[tid - ofs];
    __syncthreads();
    if (tid < 256) scan_tmp[tid] += v;
    __syncthreads();
  }
  if (tid < RSZ) {
    int ex = scan_tmp[tid] - hist[tid];
    nstart[tid] = ex;
    cursor[tid] = ex;
  }
  if (tid == RSZ - 1) nstart[RSZ] = scan_tmp[tid];
  __syncthreads();
  for (int e = tid; e < T; e += 1024) {
    unsigned pk = ebuf[e];
    int p = atomicAdd(&cursor[pk >> 16], 1);
    sorted[p] = (ushort)(pk & 0xFFFFu);
  }
  __syncthreads();

  // Per-node fp32 gather + residual + matvec. 64 groups x 16 lanes.
  int g = tid >> 4, j4 = (tid & 15) << 2;
  float s = 1.0f + eps[0];

  for (int n = g; n < RSZ; n += 64) {
    int node = r * RSZ + n;
    if (node >= N_NODES) continue;  // group-uniform

    float4 acc = *reinterpret_cast<const float4*>(feat + (node << 6) + j4);
    acc.x *= s; acc.y *= s; acc.z *= s; acc.w *= s;

    int e = nstart[n], e1 = nstart[n + 1];
    for (; e + 8 <= e1; e += 8) {
      int i0 = sorted[e + 0], i1 = sorted[e + 1], i2 = sorted[e + 2], i3 = sorted[e + 3];
      int i4_ = sorted[e + 4], i5 = sorted[e + 5], i6 = sorted[e + 6], i7 = sorted[e + 7];
      const float4 f0 = *reinterpret_cast<const float4*>(feat + (i0 << 6) + j4);
      const float4 f1 = *reinterpret_cast<const float4*>(feat + (i1 << 6) + j4);
      const float4 f2 = *reinterpret_cast<const float4*>(feat + (i2 << 6) + j4);
      const float4 f3 = *reinterpret_cast<const float4*>(feat + (i3 << 6) + j4);
      const float4 f4 = *reinterpret_cast<const float4*>(feat + (i4_ << 6) + j4);
      const float4 f5 = *reinterpret_cast<const float4*>(feat + (i5 << 6) + j4);
      const float4 f6 = *reinterpret_cast<const float4*>(feat + (i6 << 6) + j4);
      const float4 f7 = *reinterpret_cast<const float4*>(feat + (i7 << 6) + j4);
      acc.x += (f0.x + f1.x) + (f2.x + f3.x) + (f4.x + f5.x) + (f6.x + f7.x);
      acc.y += (f0.y + f1.y) + (f2.y + f3.y) + (f4.y + f5.y) + (f6.y + f7.y);
      acc.z += (f0.z + f1.z) + (f2.z + f3.z) + (f4.z + f5.z) + (f6.z + f7.z);
      acc.w += (f0.w + f1.w) + (f2.w + f3.w) + (f4.w + f5.w) + (f6.w + f7.w);
    }
    for (; e < e1; ++e) {
      int sn = sorted[e];
      const float4 f = *reinterpret_cast<const float4*>(feat + (sn << 6) + j4);
      acc.x += f.x; acc.y += f.y; acc.z += f.z; acc.w += f.w;
    }

    float4 res = *reinterpret_cast<const float4*>(b + j4);
#pragma unroll
    for (int i4 = 0; i4 < 16; ++i4) {
      float rx = __shfl(acc.x, i4, 16);
      float ry = __shfl(acc.y, i4, 16);
      float rz = __shfl(acc.z, i4, 16);
      float rw = __shfl(acc.w, i4, 16);
      const float4 w0 = *reinterpret_cast<const float4*>(Wt + ((i4 << 2) + 0) * D + j4);
      const float4 w1 = *reinterpret_cast<const float4*>(Wt + ((i4 << 2) + 1) * D + j4);
      const float4 w2 = *reinterpret_cast<const float4*>(Wt + ((i4 << 2) + 2) * D + j4);
      const float4 w3 = *reinterpret_cast<const float4*>(Wt + ((i4 << 2) + 3) * D + j4);
      res.x += rx * w0.x + ry * w1.x + rz * w2.x + rw * w3.x;
      res.y += rx * w0.y + ry * w1.y + rz * w2.y + rw * w3.y;
      res.z += rx * w0.z + ry * w1.z + rz * w2.z + rw * w3.z;
      res.w += rx * w0.w + ry * w1.w + rz * w2.w + rw * w3.w;
    }
    *reinterpret_cast<float4*>(out + (node << 6) + j4) = res;
  }
}

extern "C" void kernel_launch(void* const* d_in, const int* in_sizes, int n_in,
                              void* d_out, int out_size, void* d_ws, size_t ws_size,
                              hipStream_t stream) {
  const float* feat = (const float*)d_in[0];
  const float* W    = (const float*)d_in[1];
  const float* b    = (const float*)d_in[2];
  const float* eps  = (const float*)d_in[3];
  const int*   src  = (const int*)d_in[4];
  const int*   dst  = (const int*)d_in[5];
  float* out = (float*)d_out;

  int* ws = (int*)d_ws;
  int* cnt2      = ws + WS_CNT2;
  unsigned* rbuf = (unsigned*)(ws + WS_RBUF);

  void* args[] = {(void*)&feat, (void*)&W, (void*)&b, (void*)&eps,
                  (void*)&src, (void*)&dst, (void*)&cnt2, (void*)&rbuf,
                  (void*)&out};
  hipLaunchCooperativeKernel((const void*)gin_coop_kernel, dim3(NBLK),
                             dim3(1024), args, 0, stream);
}